// Round 13
// baseline (455.835 us; speedup 1.0000x reference)
//
#include <hip/hip_runtime.h>
#include <math.h>

#define D 256
#define V 10000
#define BB 16
#define NN 22
#define CF 400
#define CR 120
#define CA 48
#define CRP 121     // compact rows incl zero slot at 120
#define PADF 20     // LDS row stride (floats): 80B, rows cycle 8 bank-starts, 16B aligned

// ---------------- FUSED: blocks 0..199 = MLP (2 rows each); blocks 200..449 = emit partition ----
#define RT 8
#define MLPB 200
__global__ __launch_bounds__(512) void k_mlp_emit(const float* __restrict__ nt_emb,
                      const float* __restrict__ W1, const float* __restrict__ b1,
                      const float* __restrict__ resW, const float* __restrict__ resb,
                      const float* __restrict__ Wo, const float* __restrict__ bo,
                      const float* __restrict__ emit_W, const float* __restrict__ emit_b,
                      float* __restrict__ split_scores, float* __restrict__ partial) {
  int bid = blockIdx.x;
  int t = threadIdx.x;
  if (bid < MLPB) {
    __shared__ float xs[2][D], hs[2][D], ts[2][D], prt[2][2][D];
    __shared__ float redg[2][4][2];
    int c = t & 255; int h = t >> 8;
    int f0 = bid * 2;
    xs[h][c] = nt_emb[(size_t)(f0 + h) * D + c];
    __syncthreads();
    int d0 = h * 128;
    float a0 = 0.f, a1 = 0.f;
#pragma unroll 8
    for (int dd = 0; dd < 128; dd++) {
      float wv = W1[(size_t)(d0 + dd) * D + c];
      a0 += xs[0][d0 + dd] * wv; a1 += xs[1][d0 + dd] * wv;
    }
    prt[0][h][c] = a0; prt[1][h][c] = a1;
    __syncthreads();
    if (h == 0) {
      float bv = b1[c];
      hs[0][c] = prt[0][0][c] + prt[0][1][c] + bv;
      hs[1][c] = prt[1][0][c] + prt[1][1][c] + bv;
    }
    __syncthreads();
    for (int il = 0; il < 2; il++) {
      const float* W = resW + (size_t)(il * 2) * D * D;
      a0 = 0.f; a1 = 0.f;
#pragma unroll 8
      for (int dd = 0; dd < 128; dd++) {
        float wv = W[(size_t)(d0 + dd) * D + c];
        a0 += hs[0][d0 + dd] * wv; a1 += hs[1][d0 + dd] * wv;
      }
      prt[0][h][c] = a0; prt[1][h][c] = a1;
      __syncthreads();
      if (h == 0) {
        float bv = resb[(il * 2) * D + c];
        ts[0][c] = fmaxf(prt[0][0][c] + prt[0][1][c] + bv, 0.f);
        ts[1][c] = fmaxf(prt[1][0][c] + prt[1][1][c] + bv, 0.f);
      }
      __syncthreads();
      const float* W2 = resW + (size_t)(il * 2 + 1) * D * D;
      a0 = 0.f; a1 = 0.f;
#pragma unroll 8
      for (int dd = 0; dd < 128; dd++) {
        float wv = W2[(size_t)(d0 + dd) * D + c];
        a0 += ts[0][d0 + dd] * wv; a1 += ts[1][d0 + dd] * wv;
      }
      prt[0][h][c] = a0; prt[1][h][c] = a1;
      __syncthreads();
      if (h == 0) {
        float bv = resb[(il * 2 + 1) * D + c];
        hs[0][c] = fmaxf(prt[0][0][c] + prt[0][1][c] + bv, 0.f) + hs[0][c];
        hs[1][c] = fmaxf(prt[1][0][c] + prt[1][1][c] + bv, 0.f) + hs[1][c];
      }
      __syncthreads();
    }
    float y0 = hs[h][c] * Wo[c * 2 + 0], y1 = hs[h][c] * Wo[c * 2 + 1];
    for (int off = 32; off; off >>= 1) { y0 += __shfl_down(y0, off, 64); y1 += __shfl_down(y1, off, 64); }
    int wq = (t >> 6) & 3;
    if ((t & 63) == 0) { redg[h][wq][0] = y0; redg[h][wq][1] = y1; }
    __syncthreads();
    if (c == 0) {
      float s0 = redg[h][0][0] + redg[h][1][0] + redg[h][2][0] + redg[h][3][0] + bo[0];
      float s1 = redg[h][0][1] + redg[h][1][1] + redg[h][2][1] + redg[h][3][1] + bo[1];
      float m = fmaxf(s0, s1);
      float z = m + __logf(__expf(s0 - m) + __expf(s1 - m));
      split_scores[(f0 + h) * 2 + 0] = s0 - z;
      split_scores[(f0 + h) * 2 + 1] = s1 - z;
    }
  } else {
    __shared__ float exs[RT][D];
    __shared__ float ldsw[RT][8];
    int e = bid - MLPB;          // 0..249
    int y = e / 50;              // col tile 0..4 (2048 cols)
    int xt = e % 50;
    int f0 = xt * RT;
    int v0 = y * 2048 + t * 4;
    for (int idx = t; idx < RT * D; idx += 512) {
      int ri = idx >> 8, d = idx & 255;
      exs[ri][d] = nt_emb[(size_t)(f0 + ri) * D + d];
    }
    __syncthreads();
    float psum[RT];
    for (int ri = 0; ri < RT; ri++) psum[ri] = 0.f;
    if (v0 < V) {
      float acc[RT][4];
#pragma unroll
      for (int ri = 0; ri < RT; ri++)
        for (int j = 0; j < 4; j++) acc[ri][j] = 0.f;
      for (int d4 = 0; d4 < D / 4; d4++) {
        float4 w0 = *(const float4*)(emit_W + (size_t)(4 * d4 + 0) * V + v0);
        float4 w1 = *(const float4*)(emit_W + (size_t)(4 * d4 + 1) * V + v0);
        float4 w2 = *(const float4*)(emit_W + (size_t)(4 * d4 + 2) * V + v0);
        float4 w3 = *(const float4*)(emit_W + (size_t)(4 * d4 + 3) * V + v0);
#pragma unroll
        for (int ri = 0; ri < RT; ri++) {
          float4 xv = *(const float4*)(&exs[ri][4 * d4]);
          acc[ri][0] += xv.x * w0.x + xv.y * w1.x + xv.z * w2.x + xv.w * w3.x;
          acc[ri][1] += xv.x * w0.y + xv.y * w1.y + xv.z * w2.y + xv.w * w3.y;
          acc[ri][2] += xv.x * w0.z + xv.y * w1.z + xv.z * w2.z + xv.w * w3.z;
          acc[ri][3] += xv.x * w0.w + xv.y * w1.w + xv.z * w2.w + xv.w * w3.w;
        }
      }
      float4 eb = *(const float4*)(emit_b + v0);
#pragma unroll
      for (int ri = 0; ri < RT; ri++)
        psum[ri] = __expf(acc[ri][0] + eb.x) + __expf(acc[ri][1] + eb.y) +
                   __expf(acc[ri][2] + eb.z) + __expf(acc[ri][3] + eb.w);
    }
    int lane = t & 63, wid = t >> 6;
    for (int ri = 0; ri < RT; ri++) {
      float v = psum[ri];
      for (int off = 32; off; off >>= 1) v += __shfl_down(v, off, 64);
      if (lane == 0) ldsw[ri][wid] = v;
    }
    __syncthreads();
    if (t < RT) {
      float s = 0.f;
      for (int wv = 0; wv < 8; wv++) s += ldsw[t][wv];
      partial[(f0 + t) * 8 + y] = s;
    }
  }
}

// ---------------- rules pack + logZ (block CR does logZ) ----------------
__global__ void k_glgr(const float* __restrict__ rule_W, const float* __restrict__ rule_b,
                       const float* __restrict__ split_scores,
                       const int* __restrict__ lf, const int* __restrict__ rf,
                       const float* __restrict__ partialE, float* __restrict__ logZ,
                       float4* __restrict__ rules) {
  __shared__ float red[128];
  __shared__ float shv[96];
  int r = blockIdx.x;
  int t = threadIdx.x;
  if (r == CR) {
    for (int f = t; f < CF; f += 128) {
      float s = 0.f;
      for (int ct = 0; ct < 5; ct++) s += partialE[f * 8 + ct];
      logZ[f] = __logf(s);
    }
    return;
  }
  float x = (t < 96) ? (rule_W[t * CR + r] + rule_b[t]) : -INFINITY;
  red[t] = x; __syncthreads();
  for (int off = 64; off; off >>= 1) { if (t < off) red[t] = fmaxf(red[t], red[t + off]); __syncthreads(); }
  float m = red[0]; __syncthreads();
  red[t] = (t < 96) ? __expf(x - m) : 0.f; __syncthreads();
  for (int off = 64; off; off >>= 1) { if (t < off) red[t] += red[t + off]; __syncthreads(); }
  float z = m + __logf(red[0]);
  float s0 = split_scores[r * 2 + 0];
  if (t < 96) shv[t] = __expf((x - z) + s0);
  __syncthreads();
  if (t < CA) {
    float4 pk;
    pk.x = shv[t];
    pk.y = shv[CA + t];
    pk.z = __int_as_float(rf[r * CA + t]);
    pk.w = __int_as_float(lf[r * CA + t]);
    rules[r * CA + t] = pk;
  }
}

// ---------------- terminal: ET[n][f][b] = exp(term - bmax), bmax to table ----------------
__global__ __launch_bounds__(512) void k_term(const float* __restrict__ nt_emb,
                       const float* __restrict__ emit_W,
                       const float* __restrict__ emit_b, const int* __restrict__ words,
                       const float* __restrict__ split_scores, const float* __restrict__ logZ,
                       float* __restrict__ ET, float* __restrict__ bmax) {
  __shared__ float vals[CF];
  __shared__ float redw[8];
  __shared__ float mfin;
  int blk = blockIdx.x;
  int b = blk / NN, n = blk % NN;
  int t = threadIdx.x;
  int lane = t & 63, wid = t >> 6;
  int wd = words[b * NN + n];
  float wc0 = emit_W[(size_t)(4 * lane + 0) * V + wd];
  float wc1 = emit_W[(size_t)(4 * lane + 1) * V + wd];
  float wc2 = emit_W[(size_t)(4 * lane + 2) * V + wd];
  float wc3 = emit_W[(size_t)(4 * lane + 3) * V + wd];
  float eb = emit_b[wd];
  float vmax = -INFINITY;
  int fbase = wid * 50;
  for (int k = 0; k < 50; k += 2) {
    int f0 = fbase + k, f1 = f0 + 1;
    float4 xa = *(const float4*)(nt_emb + (size_t)f0 * D + 4 * lane);
    float4 xb = *(const float4*)(nt_emb + (size_t)f1 * D + 4 * lane);
    float va = xa.x * wc0 + xa.y * wc1 + xa.z * wc2 + xa.w * wc3;
    float vb = xb.x * wc0 + xb.y * wc1 + xb.z * wc2 + xb.w * wc3;
    for (int off = 32; off; off >>= 1) {
      va += __shfl_down(va, off, 64);
      vb += __shfl_down(vb, off, 64);
    }
    if (lane == 0) {
      float fa = split_scores[f0 * 2 + 1] + (va + eb) - logZ[f0];
      float fb = split_scores[f1 * 2 + 1] + (vb + eb) - logZ[f1];
      vals[f0] = fa; vals[f1] = fb;
      vmax = fmaxf(vmax, fmaxf(fa, fb));
    }
  }
  if (lane == 0) redw[wid] = vmax;
  __syncthreads();
  if (t == 0) {
    float m = redw[0];
    for (int i2 = 1; i2 < 8; i2++) m = fmaxf(m, redw[i2]);
    mfin = m;
    bmax[(n * NN + n) * BB + b] = m;
  }
  __syncthreads();
  float m = mfin;
  for (int f = t; f < CF; f += 512) ET[((size_t)n * CF + f) * BB + b] = __expf(vals[f] - m);
}

// ---------------- CKY step: ONE launch per width.  blocks [0,S) = comb(w) with inline edge k's;
// blocks [S, S+midu*rsplit) = mid partials for width w+1 (per-k normalized, no bmax dep) -------
__global__ __launch_bounds__(512) void k_cky_step(const float4* __restrict__ rules,
                      const float* __restrict__ ET, float* __restrict__ EB,
                      float* __restrict__ bmax, float* __restrict__ partA,
                      float* __restrict__ partB, int w, int S, int rsplit) {
  __shared__ float lds[21000];
  __shared__ float sM[21 * BB];
  __shared__ float Mb[BB];
  __shared__ float msum[BB];
  int t = threadIdx.x;
  int bid = blockIdx.x;
  int bq = t & 3, rr = t >> 2;
  if (bid < S) {
    // ================= comb(w) for span s=bid =================
    int s = bid, i = s, j = s + w - 1;
    int wm1 = w - 1;
    const float* partCur = (w & 1) ? partA : partB;
    if (t < wm1 * BB) {
      int k2 = t >> 4, b2 = t & 15;
      sM[k2 * BB + b2] = bmax[((size_t)i * NN + (i + k2)) * BB + b2] +
                         bmax[((size_t)(i + k2 + 1) * NN + j) * BB + b2];
    }
    __syncthreads();
    if (t < BB) {
      float M = sM[t];
      for (int k2 = 1; k2 < wm1; k2++) M = fmaxf(M, sM[k2 * BB + t]);
      Mb[t] = M;
    }
    float* SLe0 = lds;           // ET(i), CF rows
    float* SRe0 = lds + 8000;    // w==2: ET(j) CF rows; else EB(i+1,j) CRP rows
    float* SLe1 = lds + 10420;   // EB(i,j-1) CRP rows (w>2)
    float* SRe1 = lds + 12840;   // ET(j) CF rows (w>2)
    for (int idx = t; idx < CF * 4; idx += 512) {
      int f = idx >> 2, q = idx & 3;
      *(float4*)&SLe0[f * PADF + q * 4] = *(const float4*)&ET[((size_t)i * CF + f) * BB + q * 4];
    }
    if (w == 2) {
      for (int idx = t; idx < CF * 4; idx += 512) {
        int f = idx >> 2, q = idx & 3;
        *(float4*)&SRe0[f * PADF + q * 4] = *(const float4*)&ET[((size_t)j * CF + f) * BB + q * 4];
      }
    } else {
      for (int idx = t; idx < CRP * 4; idx += 512) {
        int f = idx >> 2, q = idx & 3;
        *(float4*)&SRe0[f * PADF + q * 4] = *(const float4*)&EB[(((size_t)(i + 1) * NN + j) * CRP + f) * BB + q * 4];
        *(float4*)&SLe1[f * PADF + q * 4] = *(const float4*)&EB[(((size_t)i * NN + (j - 1)) * CRP + f) * BB + q * 4];
      }
      for (int idx = t; idx < CF * 4; idx += 512) {
        int f = idx >> 2, q = idx & 3;
        *(float4*)&SRe1[f * PADF + q * 4] = *(const float4*)&ET[((size_t)j * CF + f) * BB + q * 4];
      }
    }
    __syncthreads();
    float4 acc = {0.f, 0.f, 0.f, 0.f};
    if (rr < CR) {
      const float4* rp = rules + (size_t)rr * CA;
      int boff = bq * 4;
      // ---- edge k=0: left diag ----
      {
        float4 e = {0.f, 0.f, 0.f, 0.f};
        bool rd = (w == 2);
#pragma unroll 4
        for (int a = 0; a < CA; a++) {
          float4 rule = rp[a];
          int fL = __float_as_int(rule.z);
          int fR = __float_as_int(rule.w);
          int fLc = rd ? fL : min(fL, 120);
          float4 La = *(const float4*)&SLe0[a * PADF + boff];
          float4 Ra = *(const float4*)&SRe0[a * PADF + boff];
          float4 Rg = *(const float4*)&SRe0[fLc * PADF + boff];
          float4 Lg = *(const float4*)&SLe0[fR * PADF + boff];
          e.x += rule.x * (La.x * Rg.x) + rule.y * (Lg.x * Ra.x);
          e.y += rule.x * (La.y * Rg.y) + rule.y * (Lg.y * Ra.y);
          e.z += rule.x * (La.z * Rg.z) + rule.y * (Lg.z * Ra.z);
          e.w += rule.x * (La.w * Rg.w) + rule.y * (Lg.w * Ra.w);
        }
        acc.x = e.x * __expf(sM[boff + 0] - Mb[boff + 0]);
        acc.y = e.y * __expf(sM[boff + 1] - Mb[boff + 1]);
        acc.z = e.z * __expf(sM[boff + 2] - Mb[boff + 2]);
        acc.w = e.w * __expf(sM[boff + 3] - Mb[boff + 3]);
      }
      // ---- mids k=1..w-3 (per-k normalized partials) ----
      for (int k = 1; k <= w - 3; k++) {
        float4 p = *(const float4*)&partCur[(((size_t)s * 21 + k) * CR + rr) * BB + boff];
        acc.x += p.x * __expf(sM[k * BB + boff + 0] - Mb[boff + 0]);
        acc.y += p.y * __expf(sM[k * BB + boff + 1] - Mb[boff + 1]);
        acc.z += p.z * __expf(sM[k * BB + boff + 2] - Mb[boff + 2]);
        acc.w += p.w * __expf(sM[k * BB + boff + 3] - Mb[boff + 3]);
      }
      // ---- edge k=w-2: right diag (w>2) ----
      if (w > 2) {
        float4 e = {0.f, 0.f, 0.f, 0.f};
#pragma unroll 4
        for (int a = 0; a < CA; a++) {
          float4 rule = rp[a];
          int fL = __float_as_int(rule.z);
          int fR = __float_as_int(rule.w);
          int fRc = min(fR, 120);
          float4 La = *(const float4*)&SLe1[a * PADF + boff];
          float4 Ra = *(const float4*)&SRe1[a * PADF + boff];
          float4 Rg = *(const float4*)&SRe1[fL * PADF + boff];
          float4 Lg = *(const float4*)&SLe1[fRc * PADF + boff];
          e.x += rule.x * (La.x * Rg.x) + rule.y * (Lg.x * Ra.x);
          e.y += rule.x * (La.y * Rg.y) + rule.y * (Lg.y * Ra.y);
          e.z += rule.x * (La.z * Rg.z) + rule.y * (Lg.z * Ra.z);
          e.w += rule.x * (La.w * Rg.w) + rule.y * (Lg.w * Ra.w);
        }
        int kb = (w - 2) * BB + boff;
        acc.x += e.x * __expf(sM[kb + 0] - Mb[boff + 0]);
        acc.y += e.y * __expf(sM[kb + 1] - Mb[boff + 1]);
        acc.z += e.z * __expf(sM[kb + 2] - Mb[boff + 2]);
        acc.w += e.w * __expf(sM[kb + 3] - Mb[boff + 3]);
      }
    }
    __syncthreads();                 // SL reads done; alias sums onto lds
    float* sums = lds;
    if (rr < CR) {
      sums[rr * BB + bq * 4 + 0] = acc.x;
      sums[rr * BB + bq * 4 + 1] = acc.y;
      sums[rr * BB + bq * 4 + 2] = acc.z;
      sums[rr * BB + bq * 4 + 3] = acc.w;
    }
    __syncthreads();
    if (t < BB) {
      float m = 0.f;
      for (int r2 = 0; r2 < CR; r2++) m = fmaxf(m, sums[r2 * BB + t]);
      m = fmaxf(m, 1e-35f);
      msum[t] = m;
      bmax[((size_t)i * NN + j) * BB + t] = Mb[t] + __logf(m);
    }
    __syncthreads();
    if (rr < CR) {
      float4 o;
      o.x = acc.x / msum[bq * 4 + 0];
      o.y = acc.y / msum[bq * 4 + 1];
      o.z = acc.z / msum[bq * 4 + 2];
      o.w = acc.w / msum[bq * 4 + 3];
      *(float4*)&EB[(((size_t)i * NN + j) * CRP + rr) * BB + bq * 4] = o;
    }
    if (t < BB) EB[(((size_t)i * NN + j) * CRP + 120) * BB + t] = 0.f;
  } else {
    // ================= mid partials for width W=w+1 (both children compact) =================
    int W = w + 1;
    int nmidk = W - 3;               // k in 1..W-3
    int e = bid - S;
    int rb = e % rsplit; int rem = e / rsplit;
    int k = 1 + rem % nmidk; int s = rem / nmidk;
    int i = s, j = s + W - 1;
    float* partNext = (W & 1) ? partA : partB;
    float* SL = lds;                 // CRP rows
    float* SR = lds + 2420;
    float4* sred = (float4*)(lds + 4840);
    for (int idx = t; idx < CRP * 4; idx += 512) {
      int f = idx >> 2, q = idx & 3;
      *(float4*)&SL[f * PADF + q * 4] = *(const float4*)&EB[(((size_t)i * NN + (i + k)) * CRP + f) * BB + q * 4];
      *(float4*)&SR[f * PADF + q * 4] = *(const float4*)&EB[(((size_t)(i + k + 1) * NN + j) * CRP + f) * BB + q * 4];
    }
    __syncthreads();
    int nr = CR / rsplit;
    int asplit = 128 / nr;
    float4 acc = {0.f, 0.f, 0.f, 0.f};
    bool act = (rr < nr * asplit);
    int rloc = rr % nr, asub = rr / nr;
    int r = rb * nr + rloc;
    if (act) {
      int na = CA / asplit;
      const float4* rp = rules + (size_t)r * CA + asub * na;
      int boff = bq * 4;
#pragma unroll 4
      for (int a0 = 0; a0 < na; a0++) {
        float4 rule = rp[a0];
        int fLc = min(__float_as_int(rule.z), 120);
        int fRc = min(__float_as_int(rule.w), 120);
        int a = asub * na + a0;
        float4 La = *(const float4*)&SL[a * PADF + boff];
        float4 Ra = *(const float4*)&SR[a * PADF + boff];
        float4 Rg = *(const float4*)&SR[fLc * PADF + boff];
        float4 Lg = *(const float4*)&SL[fRc * PADF + boff];
        acc.x += rule.x * (La.x * Rg.x) + rule.y * (Lg.x * Ra.x);
        acc.y += rule.x * (La.y * Rg.y) + rule.y * (Lg.y * Ra.y);
        acc.z += rule.x * (La.z * Rg.z) + rule.y * (Lg.z * Ra.z);
        acc.w += rule.x * (La.w * Rg.w) + rule.y * (Lg.w * Ra.w);
      }
    }
    if (asplit > 1) {
      sred[t] = acc;
      __syncthreads();
      if (act && asub == 0) {
        for (int s2 = 1; s2 < asplit; s2++) {
          float4 o = sred[t + s2 * nr * 4];
          acc.x += o.x; acc.y += o.y; acc.z += o.z; acc.w += o.w;
        }
      }
    }
    if (act && asub == 0) {
      *(float4*)&partNext[(((size_t)s * 21 + k) * CR + r) * BB + bq * 4] = acc;
    }
  }
}

// ---------------- final (root folded in) ----------------
__global__ __launch_bounds__(128) void k_final(const float* __restrict__ root_w,
                        const float* __restrict__ root_b, const float* __restrict__ root_mask,
                        const float* __restrict__ EB, const float* __restrict__ bmax,
                        float* __restrict__ out) {
  __shared__ float red[128];
  int b = blockIdx.x;
  int t = threadIdx.x;
  float xv[4];
  float lm = -INFINITY;
  for (int kq = 0; kq < 4; kq++) {
    int f = t + kq * 128;
    xv[kq] = (f < CF) ? (root_mask[f] + root_w[f] + root_b[f]) : -INFINITY;
    lm = fmaxf(lm, xv[kq]);
  }
  red[t] = lm; __syncthreads();
  for (int off = 64; off; off >>= 1) { if (t < off) red[t] = fmaxf(red[t], red[t + off]); __syncthreads(); }
  float M = red[0]; __syncthreads();
  float le = 0.f;
  for (int kq = 0; kq < 4; kq++) le += (t + kq * 128 < CF) ? __expf(xv[kq] - M) : 0.f;
  red[t] = le; __syncthreads();
  for (int off = 64; off; off >>= 1) { if (t < off) red[t] += red[t + off]; __syncthreads(); }
  float z = M + __logf(red[0]);
  __syncthreads();
  float x = (t < CR) ? __expf(xv[0] - z) * EB[(((size_t)0 * NN + (NN - 1)) * CRP + t) * BB + b] : 0.f;
  red[t] = x; __syncthreads();
  for (int off = 64; off; off >>= 1) { if (t < off) red[t] += red[t + off]; __syncthreads(); }
  if (t == 0) out[b] = -(bmax[(0 * NN + (NN - 1)) * BB + b] + __logf(red[0]));
}

extern "C" void kernel_launch(void* const* d_in, const int* in_sizes, int n_in,
                              void* d_out, int out_size, void* d_ws, size_t ws_size,
                              hipStream_t stream) {
  const float* nt_emb   = (const float*)d_in[1];
  const float* rule_W   = (const float*)d_in[2];
  const float* rule_b   = (const float*)d_in[3];
  const float* root_w   = (const float*)d_in[4];
  const float* root_b   = (const float*)d_in[5];
  const float* root_mask= (const float*)d_in[6];
  const float* split_W1 = (const float*)d_in[7];
  const float* split_b1 = (const float*)d_in[8];
  const float* res_W    = (const float*)d_in[9];
  const float* res_b    = (const float*)d_in[10];
  const float* split_Wo = (const float*)d_in[11];
  const float* split_bo = (const float*)d_in[12];
  const float* emit_W   = (const float*)d_in[13];
  const float* emit_b   = (const float*)d_in[14];
  const int*   words    = (const int*)d_in[15];
  const int*   lfunc    = (const int*)d_in[16];
  const int*   rfunc    = (const int*)d_in[17];

  float* ws = (float*)d_ws;
  float* ET           = ws;                          // 140800
  float* EB           = ET + NN * CF * BB;           // 937024
  float* bmaxbuf      = EB + NN * NN * CRP * BB;     // 7744
  float* partA        = bmaxbuf + NN * NN * BB;      // 21*21*120*16 = 846720 (odd widths)
  float* partB        = partA + 21 * 21 * CR * BB;   // 846720 (even widths)
  float* rules        = partB + 21 * 21 * CR * BB;   // 23040
  float* split_scores = rules + CR * CA * 4;         // 800
  float* logZ         = split_scores + 2 * CF;       // 400
  float* partialE     = logZ + CF;                   // 3200

  hipLaunchKernelGGL(k_mlp_emit, dim3(MLPB + 250), dim3(512), 0, stream, nt_emb,
                     split_W1, split_b1, res_W, res_b, split_Wo, split_bo,
                     emit_W, emit_b, split_scores, partialE);
  hipLaunchKernelGGL(k_glgr, dim3(CR + 1), dim3(128), 0, stream, rule_W, rule_b, split_scores,
                     lfunc, rfunc, partialE, logZ, (float4*)rules);
  hipLaunchKernelGGL(k_term, dim3(BB * NN), dim3(512), 0, stream, nt_emb, emit_W, emit_b,
                     words, split_scores, logZ, ET, bmaxbuf);
  for (int w = 2; w <= NN; w++) {
    int S = NN - w + 1;
    int midu = 0, rsplit = 1;
    if (w + 1 <= NN && w - 2 >= 1) {
      midu = (NN - w) * (w - 2);     // spans of width w+1 times mid-k count
      rsplit = (midu >= 224) ? 1 : ((midu >= 112) ? 2 : ((midu >= 56) ? 4 : 8));
    }
    hipLaunchKernelGGL(k_cky_step, dim3(S + midu * rsplit), dim3(512), 0, stream,
                       (const float4*)rules, ET, EB, bmaxbuf, partA, partB, w, S, rsplit);
  }
  hipLaunchKernelGGL(k_final, dim3(BB), dim3(128), 0, stream, root_w, root_b, root_mask,
                     EB, bmaxbuf, (float*)d_out);
}

// Round 14
// 345.621 us; speedup vs baseline: 1.3189x; 1.3189x over previous
//
#include <hip/hip_runtime.h>
#include <math.h>

#define D 256
#define V 10000
#define BB 16
#define NN 22
#define CF 400
#define CR 120
#define CA 48
#define CRP 121     // compact rows incl zero slot at 120
#define PADF 20     // LDS row pad (floats) -> 80B, cycles all 32 banks, 16B-aligned

// ---------------- FUSED: blocks 0..199 = MLP (2 rows each); blocks 200..449 = emit partition ----
#define RT 8
#define MLPB 200
__global__ __launch_bounds__(512) void k_mlp_emit(const float* __restrict__ nt_emb,
                      const float* __restrict__ W1, const float* __restrict__ b1,
                      const float* __restrict__ resW, const float* __restrict__ resb,
                      const float* __restrict__ Wo, const float* __restrict__ bo,
                      const float* __restrict__ emit_W, const float* __restrict__ emit_b,
                      float* __restrict__ split_scores, float* __restrict__ partial) {
  int bid = blockIdx.x;
  int t = threadIdx.x;
  if (bid < MLPB) {
    __shared__ float xs[2][D], hs[2][D], ts[2][D], prt[2][2][D];
    __shared__ float redg[2][4][2];
    int c = t & 255; int h = t >> 8;
    int f0 = bid * 2;
    xs[h][c] = nt_emb[(size_t)(f0 + h) * D + c];
    __syncthreads();
    int d0 = h * 128;
    float a0 = 0.f, a1 = 0.f;
#pragma unroll 8
    for (int dd = 0; dd < 128; dd++) {
      float wv = W1[(size_t)(d0 + dd) * D + c];
      a0 += xs[0][d0 + dd] * wv; a1 += xs[1][d0 + dd] * wv;
    }
    prt[0][h][c] = a0; prt[1][h][c] = a1;
    __syncthreads();
    if (h == 0) {
      float bv = b1[c];
      hs[0][c] = prt[0][0][c] + prt[0][1][c] + bv;
      hs[1][c] = prt[1][0][c] + prt[1][1][c] + bv;
    }
    __syncthreads();
    for (int il = 0; il < 2; il++) {
      const float* W = resW + (size_t)(il * 2) * D * D;
      a0 = 0.f; a1 = 0.f;
#pragma unroll 8
      for (int dd = 0; dd < 128; dd++) {
        float wv = W[(size_t)(d0 + dd) * D + c];
        a0 += hs[0][d0 + dd] * wv; a1 += hs[1][d0 + dd] * wv;
      }
      prt[0][h][c] = a0; prt[1][h][c] = a1;
      __syncthreads();
      if (h == 0) {
        float bv = resb[(il * 2) * D + c];
        ts[0][c] = fmaxf(prt[0][0][c] + prt[0][1][c] + bv, 0.f);
        ts[1][c] = fmaxf(prt[1][0][c] + prt[1][1][c] + bv, 0.f);
      }
      __syncthreads();
      const float* W2 = resW + (size_t)(il * 2 + 1) * D * D;
      a0 = 0.f; a1 = 0.f;
#pragma unroll 8
      for (int dd = 0; dd < 128; dd++) {
        float wv = W2[(size_t)(d0 + dd) * D + c];
        a0 += ts[0][d0 + dd] * wv; a1 += ts[1][d0 + dd] * wv;
      }
      prt[0][h][c] = a0; prt[1][h][c] = a1;
      __syncthreads();
      if (h == 0) {
        float bv = resb[(il * 2 + 1) * D + c];
        hs[0][c] = fmaxf(prt[0][0][c] + prt[0][1][c] + bv, 0.f) + hs[0][c];
        hs[1][c] = fmaxf(prt[1][0][c] + prt[1][1][c] + bv, 0.f) + hs[1][c];
      }
      __syncthreads();
    }
    float y0 = hs[h][c] * Wo[c * 2 + 0], y1 = hs[h][c] * Wo[c * 2 + 1];
    for (int off = 32; off; off >>= 1) { y0 += __shfl_down(y0, off, 64); y1 += __shfl_down(y1, off, 64); }
    int wq = (t >> 6) & 3;
    if ((t & 63) == 0) { redg[h][wq][0] = y0; redg[h][wq][1] = y1; }
    __syncthreads();
    if (c == 0) {
      float s0 = redg[h][0][0] + redg[h][1][0] + redg[h][2][0] + redg[h][3][0] + bo[0];
      float s1 = redg[h][0][1] + redg[h][1][1] + redg[h][2][1] + redg[h][3][1] + bo[1];
      float m = fmaxf(s0, s1);
      float z = m + __logf(__expf(s0 - m) + __expf(s1 - m));
      split_scores[(f0 + h) * 2 + 0] = s0 - z;
      split_scores[(f0 + h) * 2 + 1] = s1 - z;
    }
  } else {
    __shared__ float exs[RT][D];
    __shared__ float ldsw[RT][8];
    int e = bid - MLPB;          // 0..249
    int y = e / 50;              // col tile 0..4 (2048 cols)
    int xt = e % 50;
    int f0 = xt * RT;
    int v0 = y * 2048 + t * 4;
    for (int idx = t; idx < RT * D; idx += 512) {
      int ri = idx >> 8, d = idx & 255;
      exs[ri][d] = nt_emb[(size_t)(f0 + ri) * D + d];
    }
    __syncthreads();
    float psum[RT];
    for (int ri = 0; ri < RT; ri++) psum[ri] = 0.f;
    if (v0 < V) {
      float acc[RT][4];
#pragma unroll
      for (int ri = 0; ri < RT; ri++)
        for (int j = 0; j < 4; j++) acc[ri][j] = 0.f;
      for (int d4 = 0; d4 < D / 4; d4++) {
        float4 w0 = *(const float4*)(emit_W + (size_t)(4 * d4 + 0) * V + v0);
        float4 w1 = *(const float4*)(emit_W + (size_t)(4 * d4 + 1) * V + v0);
        float4 w2 = *(const float4*)(emit_W + (size_t)(4 * d4 + 2) * V + v0);
        float4 w3 = *(const float4*)(emit_W + (size_t)(4 * d4 + 3) * V + v0);
#pragma unroll
        for (int ri = 0; ri < RT; ri++) {
          float4 xv = *(const float4*)(&exs[ri][4 * d4]);
          acc[ri][0] += xv.x * w0.x + xv.y * w1.x + xv.z * w2.x + xv.w * w3.x;
          acc[ri][1] += xv.x * w0.y + xv.y * w1.y + xv.z * w2.y + xv.w * w3.y;
          acc[ri][2] += xv.x * w0.z + xv.y * w1.z + xv.z * w2.z + xv.w * w3.z;
          acc[ri][3] += xv.x * w0.w + xv.y * w1.w + xv.z * w2.w + xv.w * w3.w;
        }
      }
      float4 eb = *(const float4*)(emit_b + v0);
#pragma unroll
      for (int ri = 0; ri < RT; ri++)
        psum[ri] = __expf(acc[ri][0] + eb.x) + __expf(acc[ri][1] + eb.y) +
                   __expf(acc[ri][2] + eb.z) + __expf(acc[ri][3] + eb.w);
    }
    int lane = t & 63, wid = t >> 6;
    for (int ri = 0; ri < RT; ri++) {
      float v = psum[ri];
      for (int off = 32; off; off >>= 1) v += __shfl_down(v, off, 64);
      if (lane == 0) ldsw[ri][wid] = v;
    }
    __syncthreads();
    if (t < RT) {
      float s = 0.f;
      for (int wv = 0; wv < 8; wv++) s += ldsw[t][wv];
      partial[(f0 + t) * 8 + y] = s;
    }
  }
}

// ---------------- MERGED: blocks 0..119 rules pack; blocks 120..471 terminal w/ inline logZ ----
__global__ __launch_bounds__(512) void k_glgr_term(const float* __restrict__ rule_W,
                       const float* __restrict__ rule_b,
                       const float* __restrict__ split_scores,
                       const int* __restrict__ lf, const int* __restrict__ rf,
                       const float* __restrict__ partialE,
                       const float* __restrict__ nt_emb, const float* __restrict__ emit_W,
                       const float* __restrict__ emit_b, const int* __restrict__ words,
                       float4* __restrict__ rules,
                       float* __restrict__ ET, float* __restrict__ bmax) {
  int bid = blockIdx.x;
  int t = threadIdx.x;
  if (bid < CR) {
    // ---- rules path (only t<128 carry data; all threads hit barriers) ----
    __shared__ float red[128];
    __shared__ float shv[96];
    int r = bid;
    float x = (t < 96) ? (rule_W[t * CR + r] + rule_b[t]) : -INFINITY;
    if (t < 128) red[t] = x;
    __syncthreads();
    for (int off = 64; off; off >>= 1) { if (t < off) red[t] = fmaxf(red[t], red[t + off]); __syncthreads(); }
    float m = red[0]; __syncthreads();
    if (t < 128) red[t] = (t < 96) ? __expf(x - m) : 0.f;
    __syncthreads();
    for (int off = 64; off; off >>= 1) { if (t < off) red[t] += red[t + off]; __syncthreads(); }
    float z = m + __logf(red[0]);
    float s0 = split_scores[r * 2 + 0];
    if (t < 96) shv[t] = __expf((x - z) + s0);
    __syncthreads();
    if (t < CA) {
      float4 pk;
      pk.x = shv[t];
      pk.y = shv[CA + t];
      pk.z = __int_as_float(rf[r * CA + t]);
      pk.w = __int_as_float(lf[r * CA + t]);
      rules[r * CA + t] = pk;
    }
  } else {
    // ---- terminal path with inline logZ (identical float ops to the old k_glgr logZ) ----
    __shared__ float vals[CF];
    __shared__ float logZs[CF];
    __shared__ float redw[8];
    __shared__ float mfin;
    int blk = bid - CR;
    int b = blk / NN, n = blk % NN;
    int lane = t & 63, wid = t >> 6;
    if (t < CF) {
      float s = 0.f;
      for (int ct = 0; ct < 5; ct++) s += partialE[t * 8 + ct];
      logZs[t] = __logf(s);
    }
    __syncthreads();
    int wd = words[b * NN + n];
    float wc0 = emit_W[(size_t)(4 * lane + 0) * V + wd];
    float wc1 = emit_W[(size_t)(4 * lane + 1) * V + wd];
    float wc2 = emit_W[(size_t)(4 * lane + 2) * V + wd];
    float wc3 = emit_W[(size_t)(4 * lane + 3) * V + wd];
    float eb = emit_b[wd];
    float vmax = -INFINITY;
    int fbase = wid * 50;
    for (int k = 0; k < 50; k += 2) {
      int f0 = fbase + k, f1 = f0 + 1;
      float4 xa = *(const float4*)(nt_emb + (size_t)f0 * D + 4 * lane);
      float4 xb = *(const float4*)(nt_emb + (size_t)f1 * D + 4 * lane);
      float va = xa.x * wc0 + xa.y * wc1 + xa.z * wc2 + xa.w * wc3;
      float vb = xb.x * wc0 + xb.y * wc1 + xb.z * wc2 + xb.w * wc3;
      for (int off = 32; off; off >>= 1) {
        va += __shfl_down(va, off, 64);
        vb += __shfl_down(vb, off, 64);
      }
      if (lane == 0) {
        float fa = split_scores[f0 * 2 + 1] + (va + eb) - logZs[f0];
        float fb = split_scores[f1 * 2 + 1] + (vb + eb) - logZs[f1];
        vals[f0] = fa; vals[f1] = fb;
        vmax = fmaxf(vmax, fmaxf(fa, fb));
      }
    }
    if (lane == 0) redw[wid] = vmax;
    __syncthreads();
    if (t == 0) {
      float m = redw[0];
      for (int i2 = 1; i2 < 8; i2++) m = fmaxf(m, redw[i2]);
      mfin = m;
      bmax[(n * NN + n) * BB + b] = m;
    }
    __syncthreads();
    float m = mfin;
    for (int f = t; f < CF; f += 512) ET[((size_t)n * CF + f) * BB + b] = __expf(vals[f] - m);
  }
}

// ---------------- CKY partial: block = (s, k, r-chunk), all 16 b, float4 over b ----------------
__global__ __launch_bounds__(512) void k_cky_part(const float4* __restrict__ rules,
                      const float* __restrict__ ET, const float* __restrict__ EB,
                      const float* __restrict__ bmax, float* __restrict__ partial,
                      int w, int rsplit) {
  __shared__ float SL[CF * PADF];
  __shared__ float SR[CF * PADF];
  __shared__ float sMbuf[21 * BB];
  __shared__ float cks[BB];
  __shared__ float4 sred[512];
  int t = threadIdx.x;
  int blk = blockIdx.x;
  int rb = blk % rsplit; int rem = blk / rsplit;
  int wm1 = w - 1;
  int k = rem % wm1; int s = rem / wm1;
  int i = s, j = s + w - 1;
  bool ld = (k == 0), rd = (k == wm1 - 1);
  if (t < BB * wm1) {
    int k2 = t >> 4, b2 = t & 15;
    sMbuf[t] = bmax[(i * NN + (i + k2)) * BB + b2] + bmax[((i + k2 + 1) * NN + j) * BB + b2];
  }
  __syncthreads();
  if (t < BB) {
    float M = sMbuf[t];
    for (int k2 = 1; k2 < wm1; k2++) M = fmaxf(M, sMbuf[k2 * BB + t]);
    cks[t] = __expf(sMbuf[k * BB + t] - M);
  }
  const float* srcL = ld ? (ET + (size_t)i * CF * BB) : (EB + (size_t)(i * NN + (i + k)) * CRP * BB);
  const float* srcR = rd ? (ET + (size_t)j * CF * BB) : (EB + (size_t)((i + k + 1) * NN + j) * CRP * BB);
  int rowsL = ld ? CF : CRP, rowsR = rd ? CF : CRP;
  for (int idx = t; idx < rowsL * 4; idx += 512) {
    int f = idx >> 2, q = idx & 3;
    *(float4*)&SL[f * PADF + q * 4] = *(const float4*)&srcL[f * BB + q * 4];
  }
  for (int idx = t; idx < rowsR * 4; idx += 512) {
    int f = idx >> 2, q = idx & 3;
    *(float4*)&SR[f * PADF + q * 4] = *(const float4*)&srcR[f * BB + q * 4];
  }
  __syncthreads();
  int nr = CR / rsplit;        // 120, 60, 30, 15
  int asplit = 128 / nr;       // 1, 2, 4, 8
  int bq = t & 3, rr = t >> 2; // rr < 128
  float4 acc = {0.f, 0.f, 0.f, 0.f};
  bool act = (rr < nr * asplit);
  int rloc = rr % nr, asub = rr / nr;
  int r = rb * nr + rloc;
  if (act) {
    int na = CA / asplit;
    const float4* rp = rules + (size_t)r * CA + asub * na;
    int boff = bq * 4;
    int aB = asub * na;
#pragma unroll 4
    for (int a0 = 0; a0 < na; a0++) {
      float4 rule = rp[a0];
      int a = aB + a0;
      int fL = __float_as_int(rule.z);
      int fR = __float_as_int(rule.w);
      int fLc = rd ? fL : min(fL, 120);
      int fRc = ld ? fR : min(fR, 120);
      float4 La = *(const float4*)&SL[a * PADF + boff];
      float4 Ra = *(const float4*)&SR[a * PADF + boff];
      float4 Rg = *(const float4*)&SR[fLc * PADF + boff];
      float4 Lg = *(const float4*)&SL[fRc * PADF + boff];
      acc.x += rule.x * (La.x * Rg.x) + rule.y * (Lg.x * Ra.x);
      acc.y += rule.x * (La.y * Rg.y) + rule.y * (Lg.y * Ra.y);
      acc.z += rule.x * (La.z * Rg.z) + rule.y * (Lg.z * Ra.z);
      acc.w += rule.x * (La.w * Rg.w) + rule.y * (Lg.w * Ra.w);
    }
  }
  if (asplit > 1) {
    sred[t] = acc;
    __syncthreads();
    if (act && asub == 0) {
      for (int s2 = 1; s2 < asplit; s2++) {
        float4 o = sred[t + s2 * nr * 4];
        acc.x += o.x; acc.y += o.y; acc.z += o.z; acc.w += o.w;
      }
    }
  }
  if (act && asub == 0) {
    float4 c4 = *(const float4*)&cks[bq * 4];
    acc.x *= c4.x; acc.y *= c4.y; acc.z *= c4.z; acc.w *= c4.w;
    *(float4*)&partial[(((size_t)s * 21 + k) * CR + r) * BB + bq * 4] = acc;
  }
}

// ---------------- CKY combine: sum k-partials, renormalize to EB + bmax ----------------
__global__ __launch_bounds__(512) void k_cky_comb(const float* __restrict__ partial,
                      float* __restrict__ EB, float* __restrict__ bmax, int w) {
  __shared__ float sums[CR * BB];
  __shared__ float sMbuf[21 * BB];
  __shared__ float msum[BB];
  __shared__ float Mb[BB];
  int t = threadIdx.x;
  int s = blockIdx.x;
  int i = s, j = s + w - 1;
  int wm1 = w - 1;
  if (t < BB * wm1) {
    int k2 = t >> 4, b2 = t & 15;
    sMbuf[t] = bmax[(i * NN + (i + k2)) * BB + b2] + bmax[((i + k2 + 1) * NN + j) * BB + b2];
  }
  __syncthreads();
  if (t < BB) {
    float M = sMbuf[t];
    for (int k2 = 1; k2 < wm1; k2++) M = fmaxf(M, sMbuf[k2 * BB + t]);
    Mb[t] = M;
  }
  int bq = t & 3, rr = t >> 2;
  float4 sum = {0.f, 0.f, 0.f, 0.f};
  if (rr < CR) {
    for (int k2 = 0; k2 < wm1; k2++) {
      float4 p = *(const float4*)&partial[(((size_t)s * 21 + k2) * CR + rr) * BB + bq * 4];
      sum.x += p.x; sum.y += p.y; sum.z += p.z; sum.w += p.w;
    }
    *(float4*)&sums[rr * BB + bq * 4] = sum;
  }
  __syncthreads();
  if (t < BB) {
    float m = 0.f;
    for (int r2 = 0; r2 < CR; r2++) m = fmaxf(m, sums[r2 * BB + t]);
    m = fmaxf(m, 1e-35f);
    msum[t] = m;
    bmax[(i * NN + j) * BB + t] = Mb[t] + __logf(m);
  }
  __syncthreads();
  if (rr < CR) {
    float4 m4 = *(const float4*)&msum[bq * 4];
    sum.x /= m4.x; sum.y /= m4.y; sum.z /= m4.z; sum.w /= m4.w;
    *(float4*)&EB[(((size_t)i * NN + j) * CRP + rr) * BB + bq * 4] = sum;
  }
  if (t < BB) EB[(((size_t)i * NN + j) * CRP + 120) * BB + t] = 0.f;
}

// ---------------- final (root folded in): out[b] = -(bmax + log sum_r e^{root_r} EB[r][b]) ----------------
__global__ __launch_bounds__(128) void k_final(const float* __restrict__ root_w,
                        const float* __restrict__ root_b, const float* __restrict__ root_mask,
                        const float* __restrict__ EB, const float* __restrict__ bmax,
                        float* __restrict__ out) {
  __shared__ float red[128];
  int b = blockIdx.x;
  int t = threadIdx.x;
  float xv[4];
  float lm = -INFINITY;
  for (int kq = 0; kq < 4; kq++) {
    int f = t + kq * 128;
    xv[kq] = (f < CF) ? (root_mask[f] + root_w[f] + root_b[f]) : -INFINITY;
    lm = fmaxf(lm, xv[kq]);
  }
  red[t] = lm; __syncthreads();
  for (int off = 64; off; off >>= 1) { if (t < off) red[t] = fmaxf(red[t], red[t + off]); __syncthreads(); }
  float M = red[0]; __syncthreads();
  float le = 0.f;
  for (int kq = 0; kq < 4; kq++) le += (t + kq * 128 < CF) ? __expf(xv[kq] - M) : 0.f;
  red[t] = le; __syncthreads();
  for (int off = 64; off; off >>= 1) { if (t < off) red[t] += red[t + off]; __syncthreads(); }
  float z = M + __logf(red[0]);
  __syncthreads();
  float x = (t < CR) ? __expf(xv[0] - z) * EB[(((size_t)0 * NN + (NN - 1)) * CRP + t) * BB + b] : 0.f;
  red[t] = x; __syncthreads();
  for (int off = 64; off; off >>= 1) { if (t < off) red[t] += red[t + off]; __syncthreads(); }
  if (t == 0) out[b] = -(bmax[(0 * NN + (NN - 1)) * BB + b] + __logf(red[0]));
}

extern "C" void kernel_launch(void* const* d_in, const int* in_sizes, int n_in,
                              void* d_out, int out_size, void* d_ws, size_t ws_size,
                              hipStream_t stream) {
  const float* nt_emb   = (const float*)d_in[1];
  const float* rule_W   = (const float*)d_in[2];
  const float* rule_b   = (const float*)d_in[3];
  const float* root_w   = (const float*)d_in[4];
  const float* root_b   = (const float*)d_in[5];
  const float* root_mask= (const float*)d_in[6];
  const float* split_W1 = (const float*)d_in[7];
  const float* split_b1 = (const float*)d_in[8];
  const float* res_W    = (const float*)d_in[9];
  const float* res_b    = (const float*)d_in[10];
  const float* split_Wo = (const float*)d_in[11];
  const float* split_bo = (const float*)d_in[12];
  const float* emit_W   = (const float*)d_in[13];
  const float* emit_b   = (const float*)d_in[14];
  const int*   words    = (const int*)d_in[15];
  const int*   lfunc    = (const int*)d_in[16];
  const int*   rfunc    = (const int*)d_in[17];

  float* ws = (float*)d_ws;
  float* ET           = ws;                          // 140800
  float* EB           = ET + NN * CF * BB;           // 937024
  float* bmaxbuf      = EB + NN * NN * CRP * BB;     // 7744
  float* partialK     = bmaxbuf + NN * NN * BB;      // 846720
  float* rules        = partialK + 21 * 21 * CR * BB;// 23040
  float* split_scores = rules + CR * CA * 4;         // 800
  float* logZ         = split_scores + 2 * CF;       // 400 (unused, kept for layout)
  float* partialE     = logZ + CF;                   // 3200

  hipLaunchKernelGGL(k_mlp_emit, dim3(MLPB + 250), dim3(512), 0, stream, nt_emb,
                     split_W1, split_b1, res_W, res_b, split_Wo, split_bo,
                     emit_W, emit_b, split_scores, partialE);
  hipLaunchKernelGGL(k_glgr_term, dim3(CR + BB * NN), dim3(512), 0, stream,
                     rule_W, rule_b, split_scores, lfunc, rfunc, partialE,
                     nt_emb, emit_W, emit_b, words,
                     (float4*)rules, ET, bmaxbuf);
  for (int w = 2; w <= NN; w++) {
    int S = NN - w + 1;
    int units = S * (w - 1);
    int rsplit = (units >= 224) ? 1 : ((units >= 112) ? 2 : ((units >= 56) ? 4 : 8));
    hipLaunchKernelGGL(k_cky_part, dim3(units * rsplit), dim3(512), 0, stream,
                       (const float4*)rules, ET, EB, bmaxbuf, partialK, w, rsplit);
    hipLaunchKernelGGL(k_cky_comb, dim3(S), dim3(512), 0, stream, partialK, EB, bmaxbuf, w);
  }
  hipLaunchKernelGGL(k_final, dim3(BB), dim3(128), 0, stream, root_w, root_b, root_mask,
                     EB, bmaxbuf, (float*)d_out);
}